// Round 7
// baseline (830.357 us; speedup 1.0000x reference)
//
#include <hip/hip_runtime.h>

#define NEG_FILL (-65535.0f)   // -2^16 + 1, the mask fill value
#define NSLOT 16
#define GRID_B 1024

typedef __attribute__((ext_vector_type(8))) short  short8;   // 8 x bf16 bits
typedef __attribute__((ext_vector_type(4))) float  floatx4;  // mfma acc

__device__ inline unsigned short f2bf(float f) {             // f32 -> bf16 RNE
    unsigned u = __float_as_uint(f);
    u += 0x7FFFu + ((u >> 16) & 1u);
    return (unsigned short)(u >> 16);
}
__device__ inline float bf2f(unsigned short h) {
    return __uint_as_float(((unsigned)h) << 16);
}

// ---------------------------------------------------------------------------
// init: zero slots (65536 f), B0 = Binit (4096), zero barrier words (256).
// grid = 256 x 256.
__global__ __launch_bounds__(256) void k_init(const float* __restrict__ Binit,
                                              float* __restrict__ B0,
                                              float* __restrict__ slots,
                                              unsigned* __restrict__ bars) {
    int i = blockIdx.x * 256 + threadIdx.x;
    slots[i] = 0.f;
    if (i < 4096) B0[i] = Binit[i];
    if (i < 256) bars[i] = 0u;
}

// ---------------------------------------------------------------------------
// Grid barrier: counter at w[0], release flag at w[32] (separate lines).
// Arrive with acq_rel (release = writeback this XCD's dirty L2: slot zeros,
// Bn writes); waiters spin on acquire loads (invalidate L1/L2 on exit).
__device__ __forceinline__ void gbar(unsigned* w) {
    __syncthreads();
    if (threadIdx.x == 0) {
        if (__hip_atomic_fetch_add(w, 1u, __ATOMIC_ACQ_REL,
                                   __HIP_MEMORY_SCOPE_AGENT) == GRID_B - 1u) {
            __hip_atomic_store(w + 32, 1u, __ATOMIC_RELEASE,
                               __HIP_MEMORY_SCOPE_AGENT);
        } else {
            while (__hip_atomic_load(w + 32, __ATOMIC_ACQUIRE,
                                     __HIP_MEMORY_SCOPE_AGENT) == 0u)
                __builtin_amdgcn_s_sleep(8);
        }
    }
    __syncthreads();
}

// ---------------------------------------------------------------------------
// Persistent kernel: all 3 routing iterations. 1024 blocks x 256 thr,
// exactly 4 blocks/CU co-resident (LDS 27.6 KB, VGPR <= 128 via bounds).
// Iteration 0 fuses ln = low@S (MFMA) with the T accumulation (C-fragment
// reuse); iterations 1-2 read the stored bf16 ln. B-reduce in-kernel.
__global__ __launch_bounds__(256, 4) void k_mega(
    const float* __restrict__ low,       // [1024,512,64] f32
    const float* __restrict__ S,         // [64,64] f32
    const int* __restrict__ seq_len,     // [1024]
    unsigned short* __restrict__ ln,     // ws: [1024,512,64] bf16
    float* __restrict__ slots,           // ws: [NSLOT][4096]
    float* __restrict__ B0,              // ws: [4096] (holds Binit)
    float* __restrict__ B1,              // ws: [4096]
    unsigned* __restrict__ bars,         // ws: 4 barriers x 64 words
    float* __restrict__ out)             // [1024,8,64] f32
{
    __shared__ __align__(16) float WsT[512][8];        // W transposed
    __shared__ __align__(16) float Tpart[4][8][64];    // per-wave T partials
    __shared__ __align__(16) float Tred[8][64];        // reduced T
    __shared__ __align__(16) unsigned short Hn[8][64]; // high, bf16

    const int t = threadIdx.x, lane = t & 63, g = t >> 6, b = blockIdx.x;
    const int m = lane & 15, q = lane >> 4;
    const int sl = seq_len[b];
    const float* lowb = low + ((size_t)b << 15);
    unsigned short* lnb = ln + ((size_t)b << 15);

    float* Bc = B0;                       // current B (read)
    float* Bn = B1;                       // next B (written by B-red)

    for (int it = 0; it < 3; ++it) {
        // ---- masked softmax, wave-local; wave g owns k=g, g+4 -------------
        #pragma unroll
        for (int kk = 0; kk < 2; ++kk) {
            const int k = g + (kk << 2);
            float v[8];
            float mx = NEG_FILL;
            #pragma unroll
            for (int j = 0; j < 8; ++j) {
                int l = lane + (j << 6);
                v[j] = (l < sl) ? Bc[(k << 9) + l] : NEG_FILL;
                mx = fmaxf(mx, v[j]);
            }
            #pragma unroll
            for (int off = 32; off; off >>= 1) mx = fmaxf(mx, __shfl_xor(mx, off));
            float s = 0.f;
            #pragma unroll
            for (int j = 0; j < 8; ++j) { v[j] = expf(v[j] - mx); s += v[j]; }
            #pragma unroll
            for (int off = 32; off; off >>= 1) s += __shfl_xor(s, off);
            const float inv = 1.0f / s;
            #pragma unroll
            for (int j = 0; j < 8; ++j) WsT[lane + (j << 6)][k] = v[j] * inv;
        }
        __syncthreads();

        if (it == 0) {
            // ---- fused: ln tiles via MFMA + T accumulation from C-frags ---
            short8 sfrag[4][2];           // B[k=d][n=o]: o = nt*16+m, d = dh*32+q*8+j
            #pragma unroll
            for (int nt = 0; nt < 4; ++nt)
                #pragma unroll
                for (int dh = 0; dh < 2; ++dh) {
                    short8 f;
                    #pragma unroll
                    for (int j = 0; j < 8; ++j) {
                        int d = dh * 32 + q * 8 + j;
                        f[j] = (short)f2bf(S[(d << 6) + nt * 16 + m]);
                    }
                    sfrag[nt][dh] = f;
                }
            float Tp[8][4];
            #pragma unroll
            for (int k = 0; k < 8; ++k)
                #pragma unroll
                for (int nt = 0; nt < 4; ++nt) Tp[k][nt] = 0.f;

            for (int tt = 0; tt < 8; ++tt) {
                const int lt = (g << 7) + (tt << 4);
                short8 afrag[2];          // A[m=l][k=d]
                #pragma unroll
                for (int dh = 0; dh < 2; ++dh) {
                    const float4* p =
                        (const float4*)&lowb[((lt + m) << 6) + dh * 32 + q * 8];
                    float4 x0 = p[0], x1 = p[1];
                    short8 f;
                    f[0] = (short)f2bf(x0.x); f[1] = (short)f2bf(x0.y);
                    f[2] = (short)f2bf(x0.z); f[3] = (short)f2bf(x0.w);
                    f[4] = (short)f2bf(x1.x); f[5] = (short)f2bf(x1.y);
                    f[6] = (short)f2bf(x1.z); f[7] = (short)f2bf(x1.w);
                    afrag[dh] = f;
                }
                float lnr[4][4];          // [r][nt] bf16-rounded ln values
                #pragma unroll
                for (int nt = 0; nt < 4; ++nt) {
                    floatx4 acc = {0.f, 0.f, 0.f, 0.f};
                    acc = __builtin_amdgcn_mfma_f32_16x16x32_bf16(afrag[0], sfrag[nt][0], acc, 0, 0, 0);
                    acc = __builtin_amdgcn_mfma_f32_16x16x32_bf16(afrag[1], sfrag[nt][1], acc, 0, 0, 0);
                    // C: row = q*4+r (l-within-tile), col = nt*16+m (o)
                    #pragma unroll
                    for (int r = 0; r < 4; ++r) {
                        unsigned short hb = f2bf(acc[r]);
                        lnb[((size_t)(lt + (q << 2) + r) << 6) + nt * 16 + m] = hb;
                        lnr[r][nt] = bf2f(hb);   // keep numerics == stored ln
                    }
                }
                #pragma unroll
                for (int r = 0; r < 4; ++r) {
                    const int l = lt + (q << 2) + r;
                    const float4 wa = *(const float4*)&WsT[l][0];
                    const float4 wb = *(const float4*)&WsT[l][4];
                    #pragma unroll
                    for (int nt = 0; nt < 4; ++nt) {
                        const float x = lnr[r][nt];
                        Tp[0][nt] = fmaf(wa.x, x, Tp[0][nt]);
                        Tp[1][nt] = fmaf(wa.y, x, Tp[1][nt]);
                        Tp[2][nt] = fmaf(wa.z, x, Tp[2][nt]);
                        Tp[3][nt] = fmaf(wa.w, x, Tp[3][nt]);
                        Tp[4][nt] = fmaf(wb.x, x, Tp[4][nt]);
                        Tp[5][nt] = fmaf(wb.y, x, Tp[5][nt]);
                        Tp[6][nt] = fmaf(wb.z, x, Tp[6][nt]);
                        Tp[7][nt] = fmaf(wb.w, x, Tp[7][nt]);
                    }
                }
            }
            // butterfly over q (lanes m, m+16, m+32, m+48): sum wave's 128 rows
            #pragma unroll
            for (int k = 0; k < 8; ++k)
                #pragma unroll
                for (int nt = 0; nt < 4; ++nt) {
                    float v = Tp[k][nt];
                    v += __shfl_xor(v, 16);
                    v += __shfl_xor(v, 32);
                    Tp[k][nt] = v;
                }
            // lane = q*16+m holds o=lane via nt=q
            #pragma unroll
            for (int k = 0; k < 8; ++k) Tpart[g][k][lane] = Tp[k][q];
            __syncthreads();
        } else {
            // ---- T-phase from stored ln: 4 rows per 8B load ---------------
            floatx4 Tacc[8];
            #pragma unroll
            for (int k = 0; k < 8; ++k) Tacc[k] = (floatx4){0.f, 0.f, 0.f, 0.f};
            const int l0 = g << 7;
            #pragma unroll 2
            for (int itr = 0; itr < 32; ++itr) {
                const int l = l0 + (itr << 2) + q;
                const uint2 u = *(const uint2*)&lnb[(l << 6) + (m << 2)];
                const float x0 = __uint_as_float(u.x << 16);
                const float x1 = __uint_as_float(u.x & 0xFFFF0000u);
                const float x2 = __uint_as_float(u.y << 16);
                const float x3 = __uint_as_float(u.y & 0xFFFF0000u);
                const float4 wa = *(const float4*)&WsT[l][0];
                const float4 wb = *(const float4*)&WsT[l][4];
#define TROW(K, WV)                                          \
                Tacc[K][0] = fmaf(WV, x0, Tacc[K][0]);       \
                Tacc[K][1] = fmaf(WV, x1, Tacc[K][1]);       \
                Tacc[K][2] = fmaf(WV, x2, Tacc[K][2]);       \
                Tacc[K][3] = fmaf(WV, x3, Tacc[K][3]);
                TROW(0, wa.x) TROW(1, wa.y) TROW(2, wa.z) TROW(3, wa.w)
                TROW(4, wb.x) TROW(5, wb.y) TROW(6, wb.z) TROW(7, wb.w)
#undef TROW
            }
            #pragma unroll
            for (int k = 0; k < 8; ++k)
                #pragma unroll
                for (int j = 0; j < 4; ++j) {
                    float v = Tacc[k][j];
                    v += __shfl_xor(v, 16);
                    v += __shfl_xor(v, 32);
                    Tacc[k][j] = v;
                }
            if (q == 0) {
                #pragma unroll
                for (int k = 0; k < 8; ++k)
                    *(float4*)&Tpart[g][k][m << 2] =
                        make_float4(Tacc[k][0], Tacc[k][1], Tacc[k][2], Tacc[k][3]);
            }
            __syncthreads();
        }

        // ---- cross-wave reduce: 512 values, 256 threads x 2 ---------------
        #pragma unroll
        for (int idx = t; idx < 512; idx += 256) {
            float s = (&Tpart[0][0][0])[idx] + (&Tpart[1][0][0])[idx]
                    + (&Tpart[2][0][0])[idx] + (&Tpart[3][0][0])[idx];
            (&Tred[0][0])[idx] = s;
        }
        __syncthreads();

        // ---- squash over K; thread (g, lane=o) owns k=g, g+4 --------------
        float sq = 0.f;
        #pragma unroll
        for (int k = 0; k < 8; ++k) { float x = Tred[k][lane]; sq = fmaf(x, x, sq); }
        const float scale = sq / (1.0f + sq) / sqrtf(sq + 1e-9f);
        const float hf0 = scale * Tred[g][lane];
        const float hf1 = scale * Tred[g + 4][lane];

        if (it == 2) {
            out[(((size_t)b * 8 + g)     << 6) + lane] = hf0;
            out[(((size_t)b * 8 + g + 4) << 6) + lane] = hf1;
            return;
        }
        Hn[g][lane]     = f2bf(hf0);
        Hn[g + 4][lane] = f2bf(hf1);
        __syncthreads();

        // ---- delta = high @ ln^T via MFMA; atomic into this block's slot --
        float* slot = slots + ((b & (NSLOT - 1)) << 12);
        short8 afragH[2];                 // A[m=k_c][k=o], valid m < 8
        #pragma unroll
        for (int oh = 0; oh < 2; ++oh) {
            short8 f = {0, 0, 0, 0, 0, 0, 0, 0};
            if (m < 8) f = *(const short8*)&Hn[m][oh * 32 + q * 8];
            afragH[oh] = f;
        }
        #pragma unroll 2
        for (int tt = 0; tt < 8; ++tt) {
            const int lt = (g << 7) + (tt << 4);
            floatx4 acc = {0.f, 0.f, 0.f, 0.f};
            #pragma unroll
            for (int oh = 0; oh < 2; ++oh) {
                const short8 bfrag =
                    *(const short8*)&lnb[((lt + m) << 6) + oh * 32 + q * 8];
                acc = __builtin_amdgcn_mfma_f32_16x16x32_bf16(afragH[oh], bfrag, acc, 0, 0, 0);
            }
            if (q < 2) {
                #pragma unroll
                for (int r = 0; r < 4; ++r)
                    atomicAdd(&slot[(q * 4 + r) * 512 + lt + m], acc[r]);
            }
        }

        // ---- grid barrier, B-reduce (blocks 0-15), grid barrier -----------
        gbar(bars + it * 128);
        if (b < 16) {
            const int i = (b << 8) + t;             // 0..4095
            float s2 = Bc[i];
            #pragma unroll
            for (int s = 0; s < NSLOT; ++s) {
                s2 += slots[s * 4096 + i];
                slots[s * 4096 + i] = 0.f;
            }
            Bn[i] = s2;
        }
        gbar(bars + it * 128 + 64);
        float* tmp = Bc; Bc = Bn; Bn = tmp;         // ping-pong
    }
}

// ===========================================================================
// Fallback (round-4 verified path) — used only if ws_size is too small.
__global__ __launch_bounds__(256) void k_copy4k(const float* __restrict__ src,
                                                float* __restrict__ dst) {
    int i = blockIdx.x * 256 + threadIdx.x;
    dst[i] = src[i];
}

__global__ __launch_bounds__(256, 4) void k_route(
    const float* __restrict__ low, const float* __restrict__ S,
    const float* __restrict__ Bcur, float* __restrict__ Bnext,
    const int* __restrict__ seq_len, float* __restrict__ out, int last)
{
    __shared__ float smemA[64 * 65];
    __shared__ float Spad[64][65];
    __shared__ float GT[64][8];
    __shared__ float Tred[8][64];
    float* WsT = smemA;
    float (*Tpart)[8][64] = (float (*)[8][64])smemA;
    float (*tile)[65]     = (float (*)[65])smemA;

    const int t = threadIdx.x, o = t & 63, g = t >> 6, b = blockIdx.x;
    const int sl = seq_len[b];
    const float* lowb = low + ((size_t)b << 15);

    #pragma unroll
    for (int i = 0; i < 16; ++i) {
        int idx = t + (i << 8);
        Spad[idx >> 6][idx & 63] = S[idx];
    }
    #pragma unroll
    for (int kk = 0; kk < 2; ++kk) {
        const int k = g + (kk << 2);
        float v[8];
        float mx = NEG_FILL;
        #pragma unroll
        for (int j = 0; j < 8; ++j) {
            int l = o + (j << 6);
            v[j] = (l < sl) ? Bcur[(k << 9) + l] : NEG_FILL;
            mx = fmaxf(mx, v[j]);
        }
        #pragma unroll
        for (int off = 32; off; off >>= 1) mx = fmaxf(mx, __shfl_xor(mx, off));
        float s = 0.f;
        #pragma unroll
        for (int j = 0; j < 8; ++j) { v[j] = expf(v[j] - mx); s += v[j]; }
        #pragma unroll
        for (int off = 32; off; off >>= 1) s += __shfl_xor(s, off);
        const float inv = 1.0f / s;
        #pragma unroll
        for (int j = 0; j < 8; ++j) WsT[((o + (j << 6)) << 3) + k] = v[j] * inv;
    }
    __syncthreads();

    float Ta[8];
    #pragma unroll
    for (int k = 0; k < 8; ++k) Ta[k] = 0.f;
    {
        const int l0 = g << 7;
        #pragma unroll 4
        for (int i = 0; i < 128; ++i) {
            const int l = l0 + i;
            const float x = lowb[(l << 6) + o];
            const float4 wa = *(const float4*)&WsT[(l << 3)];
            const float4 wb = *(const float4*)&WsT[(l << 3) + 4];
            Ta[0] = fmaf(wa.x, x, Ta[0]); Ta[1] = fmaf(wa.y, x, Ta[1]);
            Ta[2] = fmaf(wa.z, x, Ta[2]); Ta[3] = fmaf(wa.w, x, Ta[3]);
            Ta[4] = fmaf(wb.x, x, Ta[4]); Ta[5] = fmaf(wb.y, x, Ta[5]);
            Ta[6] = fmaf(wb.z, x, Ta[6]); Ta[7] = fmaf(wb.w, x, Ta[7]);
        }
    }
    __syncthreads();
    #pragma unroll
    for (int k = 0; k < 8; ++k) Tpart[g][k][o] = Ta[k];
    __syncthreads();

    float h0 = 0.f, h1 = 0.f;
    #pragma unroll
    for (int gg = 0; gg < 4; ++gg) { h0 += Tpart[gg][g][o]; h1 += Tpart[gg][g + 4][o]; }
    Tred[g][o] = h0; Tred[g + 4][o] = h1;
    __syncthreads();

    float hp0 = 0.f, hp1 = 0.f;
    #pragma unroll
    for (int d = 0; d < 64; ++d) {
        const float sv = Spad[d][o];
        hp0 = fmaf(Tred[g][d], sv, hp0);
        hp1 = fmaf(Tred[g + 4][d], sv, hp1);
    }
    __syncthreads();
    Tred[g][o] = hp0; Tred[g + 4][o] = hp1;
    __syncthreads();

    float sq = 0.f;
    #pragma unroll
    for (int k = 0; k < 8; ++k) { float x = Tred[k][o]; sq = fmaf(x, x, sq); }
    const float scale = sq / (1.0f + sq) / sqrtf(sq + 1e-9f);
    const float hf0 = scale * hp0;
    const float hf1 = scale * hp1;

    if (last) {
        out[(((size_t)b * 8 + g)     << 6) + o] = hf0;
        out[(((size_t)b * 8 + g + 4) << 6) + o] = hf1;
        return;
    }
    __syncthreads();
    Tred[g][o] = hf0; Tred[g + 4][o] = hf1;
    __syncthreads();

    float g0 = 0.f, g1 = 0.f;
    #pragma unroll
    for (int oo = 0; oo < 64; ++oo) {
        const float sv = Spad[o][oo];
        g0 = fmaf(Tred[g][oo], sv, g0);
        g1 = fmaf(Tred[g + 4][oo], sv, g1);
    }
    GT[o][g] = g0; GT[o][g + 4] = g1;
    __syncthreads();

    for (int c = 0; c < 8; ++c) {
        const int lc = c << 6;
        #pragma unroll
        for (int r = 0; r < 16; ++r) {
            const int lr = (g << 4) + r;
            tile[lr][o] = lowb[((lc + lr) << 6) + o];
        }
        __syncthreads();
        float a0 = 0.f, a1 = 0.f;
        #pragma unroll
        for (int d = 0; d < 64; ++d) {
            const float x = tile[o][d];
            a0 = fmaf(GT[d][g], x, a0);
            a1 = fmaf(GT[d][g + 4], x, a1);
        }
        atomicAdd(&Bnext[(g << 9) + lc + o], a0);
        atomicAdd(&Bnext[((g + 4) << 9) + lc + o], a1);
        __syncthreads();
    }
}

// ---------------------------------------------------------------------------
extern "C" void kernel_launch(void* const* d_in, const int* in_sizes, int n_in,
                              void* d_out, int out_size, void* d_ws, size_t ws_size,
                              hipStream_t stream) {
    const float* low   = (const float*)d_in[0];   // [1024,512,64]
    const float* Binit = (const float*)d_in[1];   // [1,8,512]
    const float* S     = (const float*)d_in[2];   // [64,64]
    const int*   seq   = (const int*)d_in[3];     // [1024,1]
    float* outp = (float*)d_out;                  // [1024,8,64] f32

    const size_t LN_BYTES   = (size_t)1024 * 512 * 64 * 2;       // 67.1 MB
    const size_t SLOT_BYTES = (size_t)NSLOT * 4096 * sizeof(float);
    const size_t B_BYTES    = 4096 * sizeof(float);
    const size_t BAR_BYTES  = 512 * sizeof(unsigned);
    const size_t NEED = LN_BYTES + SLOT_BYTES + 2 * B_BYTES + BAR_BYTES;

    if (ws_size >= NEED) {
        unsigned short* lnw = (unsigned short*)d_ws;
        float* slots = (float*)((char*)d_ws + LN_BYTES);
        float* B0 = slots + (size_t)NSLOT * 4096;
        float* B1 = B0 + 4096;
        unsigned* bars = (unsigned*)(B1 + 4096);

        k_init<<<256, 256, 0, stream>>>(Binit, B0, slots, bars);
        k_mega<<<GRID_B, 256, 0, stream>>>(low, S, seq, lnw, slots, B0, B1,
                                           bars, outp);
    } else {
        // fallback: round-4 verified path (ws >= 32 KB)
        float* B0 = (float*)d_ws;
        float* B1 = B0 + 4096;
        k_copy4k<<<16, 256, 0, stream>>>(Binit, B0);
        k_copy4k<<<16, 256, 0, stream>>>(B0, B1);
        k_route<<<1024, 256, 0, stream>>>(low, S, B0, B1, seq, outp, 0);
        k_copy4k<<<16, 256, 0, stream>>>(B1, B0);
        k_route<<<1024, 256, 0, stream>>>(low, S, B1, B0, seq, outp, 0);
        k_route<<<1024, 256, 0, stream>>>(low, S, B0, nullptr, seq, outp, 1);
    }
}

// Round 8
// 284.277 us; speedup vs baseline: 2.9209x; 2.9209x over previous
//
#include <hip/hip_runtime.h>

#define NEG_FILL (-65535.0f)   // -2^16 + 1, the mask fill value
#define NSLOT 32

typedef __attribute__((ext_vector_type(8))) short  short8;   // 8 x bf16 bits
typedef __attribute__((ext_vector_type(4))) float  floatx4;  // mfma acc

__device__ inline unsigned short f2bf(float f) {             // f32 -> bf16 RNE
    unsigned u = __float_as_uint(f);
    u += 0x7FFFu + ((u >> 16) & 1u);
    return (unsigned short)(u >> 16);
}
__device__ inline float bf2f(unsigned short h) {
    return __uint_as_float(((unsigned)h) << 16);
}

// ---------------------------------------------------------------------------
// init: zero slots (NSLOT*4096 f), B0 = Binit (4096). grid = 512 x 256.
__global__ __launch_bounds__(256) void k_init(const float* __restrict__ Binit,
                                              float* __restrict__ B0,
                                              float* __restrict__ slots) {
    int i = blockIdx.x * 256 + threadIdx.x;
    slots[i] = 0.f;
    if (i < 4096) B0[i] = Binit[i];
}

// ---------------------------------------------------------------------------
// Bnext = Bcur + sum_s slots[s]; re-zero slots. grid = 16 x 256.
__global__ __launch_bounds__(256) void k_bred(const float* __restrict__ Bcur,
                                              float* __restrict__ Bnext,
                                              float* __restrict__ slots) {
    int i = blockIdx.x * 256 + threadIdx.x;       // 0..4095
    float s = Bcur[i];
    #pragma unroll
    for (int j = 0; j < NSLOT; ++j) {
        s += slots[j * 4096 + i];
        slots[j * 4096 + i] = 0.f;
    }
    Bnext[i] = s;
}

// ---------------------------------------------------------------------------
// Shared device helpers for the routing kernels.
__device__ __forceinline__ void softmax_to_WsT(
    const float* __restrict__ Bc, int sl, int lane, int g,
    float (*WsT)[8]) {
    #pragma unroll
    for (int kk = 0; kk < 2; ++kk) {
        const int k = g + (kk << 2);
        float v[8];
        float mx = NEG_FILL;
        #pragma unroll
        for (int j = 0; j < 8; ++j) {
            int l = lane + (j << 6);
            v[j] = (l < sl) ? Bc[(k << 9) + l] : NEG_FILL;
            mx = fmaxf(mx, v[j]);
        }
        #pragma unroll
        for (int off = 32; off; off >>= 1) mx = fmaxf(mx, __shfl_xor(mx, off));
        float s = 0.f;
        #pragma unroll
        for (int j = 0; j < 8; ++j) { v[j] = expf(v[j] - mx); s += v[j]; }
        #pragma unroll
        for (int off = 32; off; off >>= 1) s += __shfl_xor(s, off);
        const float inv = 1.0f / s;
        #pragma unroll
        for (int j = 0; j < 8; ++j) WsT[lane + (j << 6)][k] = v[j] * inv;
    }
}

// delta = high @ ln^T via MFMA, batched loads, atomics into slot.
__device__ __forceinline__ void delta_phase(
    const unsigned short* __restrict__ lnb, const unsigned short (*Hn)[64],
    float* __restrict__ slot, int g, int m, int q) {
    short8 afragH[2];                 // A[m=k_c][k=o], valid m < 8
    #pragma unroll
    for (int oh = 0; oh < 2; ++oh) {
        short8 f = {0, 0, 0, 0, 0, 0, 0, 0};
        if (m < 8) f = *(const short8*)&Hn[m][oh * 32 + q * 8];
        afragH[oh] = f;
    }
    #pragma unroll
    for (int half = 0; half < 2; ++half) {
        short8 bf[4][2];
        #pragma unroll
        for (int t2 = 0; t2 < 4; ++t2) {          // 8 loads in flight
            const int lt = (g << 7) + (((half << 2) + t2) << 4);
            const unsigned short* p = &lnb[((lt + m) << 6) + q * 8];
            bf[t2][0] = *(const short8*)p;
            bf[t2][1] = *(const short8*)(p + 32);
        }
        #pragma unroll
        for (int t2 = 0; t2 < 4; ++t2) {
            const int lt = (g << 7) + (((half << 2) + t2) << 4);
            floatx4 acc = {0.f, 0.f, 0.f, 0.f};
            acc = __builtin_amdgcn_mfma_f32_16x16x32_bf16(afragH[0], bf[t2][0], acc, 0, 0, 0);
            acc = __builtin_amdgcn_mfma_f32_16x16x32_bf16(afragH[1], bf[t2][1], acc, 0, 0, 0);
            if (q < 2) {
                #pragma unroll
                for (int r = 0; r < 4; ++r)
                    atomicAdd(&slot[(q * 4 + r) * 512 + lt + m], acc[r]);
            }
        }
    }
}

// ---------------------------------------------------------------------------
// Iteration 0, fused: softmax(Binit) + ln = low@S (MFMA, stored bf16) with
// T accumulated directly from the bf16-rounded C-fragments (block-local, no
// grid sync needed), squash, delta -> slots.
__global__ __launch_bounds__(256, 4) void k_fused0(
    const float* __restrict__ low,       // [1024,512,64] f32
    const float* __restrict__ S,         // [64,64] f32
    const float* __restrict__ Bc,        // [4096] (= Binit)
    float* __restrict__ slots,           // [NSLOT][4096]
    const int* __restrict__ seq_len,     // [1024]
    unsigned short* __restrict__ ln)     // [1024,512,64] bf16 out
{
    __shared__ __align__(16) float WsT[512][8];
    __shared__ __align__(16) float Tpart[4][8][64];
    __shared__ __align__(16) float Tred[8][64];
    __shared__ __align__(16) unsigned short Hn[8][64];

    const int t = threadIdx.x, lane = t & 63, g = t >> 6, b = blockIdx.x;
    const int m = lane & 15, q = lane >> 4;
    const int sl = seq_len[b];
    const float* lowb = low + ((size_t)b << 15);
    unsigned short* lnb = ln + ((size_t)b << 15);

    softmax_to_WsT(Bc, sl, lane, g, WsT);
    __syncthreads();

    // B-frags for S: B[k=d][n=o]: o = nt*16+m, d = dh*32 + q*8 + j
    short8 sfrag[4][2];
    #pragma unroll
    for (int nt = 0; nt < 4; ++nt)
        #pragma unroll
        for (int dh = 0; dh < 2; ++dh) {
            short8 f;
            #pragma unroll
            for (int j = 0; j < 8; ++j) {
                int d = dh * 32 + q * 8 + j;
                f[j] = (short)f2bf(S[(d << 6) + nt * 16 + m]);
            }
            sfrag[nt][dh] = f;
        }

    float Tp[8][4];
    #pragma unroll
    for (int k = 0; k < 8; ++k)
        #pragma unroll
        for (int nt = 0; nt < 4; ++nt) Tp[k][nt] = 0.f;

    for (int tt = 0; tt < 8; ++tt) {
        const int lt = (g << 7) + (tt << 4);
        short8 afrag[2];              // A[m=l][k=d]
        #pragma unroll
        for (int dh = 0; dh < 2; ++dh) {
            const float4* p =
                (const float4*)&lowb[((lt + m) << 6) + dh * 32 + q * 8];
            float4 x0 = p[0], x1 = p[1];
            short8 f;
            f[0] = (short)f2bf(x0.x); f[1] = (short)f2bf(x0.y);
            f[2] = (short)f2bf(x0.z); f[3] = (short)f2bf(x0.w);
            f[4] = (short)f2bf(x1.x); f[5] = (short)f2bf(x1.y);
            f[6] = (short)f2bf(x1.z); f[7] = (short)f2bf(x1.w);
            afrag[dh] = f;
        }
        float lnr[4][4];              // [r][nt] bf16-rounded ln values
        #pragma unroll
        for (int nt = 0; nt < 4; ++nt) {
            floatx4 acc = {0.f, 0.f, 0.f, 0.f};
            acc = __builtin_amdgcn_mfma_f32_16x16x32_bf16(afrag[0], sfrag[nt][0], acc, 0, 0, 0);
            acc = __builtin_amdgcn_mfma_f32_16x16x32_bf16(afrag[1], sfrag[nt][1], acc, 0, 0, 0);
            // C: row = q*4+r (l-within-tile), col = nt*16+m (o)
            #pragma unroll
            for (int r = 0; r < 4; ++r) {
                unsigned short hb = f2bf(acc[r]);
                lnb[((size_t)(lt + (q << 2) + r) << 6) + nt * 16 + m] = hb;
                lnr[r][nt] = bf2f(hb);     // numerics == stored ln
            }
        }
        #pragma unroll
        for (int r = 0; r < 4; ++r) {
            const int l = lt + (q << 2) + r;
            const float4 wa = *(const float4*)&WsT[l][0];
            const float4 wb = *(const float4*)&WsT[l][4];
            #pragma unroll
            for (int nt = 0; nt < 4; ++nt) {
                const float x = lnr[r][nt];
                Tp[0][nt] = fmaf(wa.x, x, Tp[0][nt]);
                Tp[1][nt] = fmaf(wa.y, x, Tp[1][nt]);
                Tp[2][nt] = fmaf(wa.z, x, Tp[2][nt]);
                Tp[3][nt] = fmaf(wa.w, x, Tp[3][nt]);
                Tp[4][nt] = fmaf(wb.x, x, Tp[4][nt]);
                Tp[5][nt] = fmaf(wb.y, x, Tp[5][nt]);
                Tp[6][nt] = fmaf(wb.z, x, Tp[6][nt]);
                Tp[7][nt] = fmaf(wb.w, x, Tp[7][nt]);
            }
        }
    }
    // butterfly over q: sum the wave's 128 rows
    #pragma unroll
    for (int k = 0; k < 8; ++k)
        #pragma unroll
        for (int nt = 0; nt < 4; ++nt) {
            float v = Tp[k][nt];
            v += __shfl_xor(v, 16);
            v += __shfl_xor(v, 32);
            Tp[k][nt] = v;
        }
    #pragma unroll
    for (int k = 0; k < 8; ++k) Tpart[g][k][lane] = Tp[k][q];  // o = lane
    __syncthreads();

    #pragma unroll
    for (int idx = t; idx < 512; idx += 256) {
        float s = (&Tpart[0][0][0])[idx] + (&Tpart[1][0][0])[idx]
                + (&Tpart[2][0][0])[idx] + (&Tpart[3][0][0])[idx];
        (&Tred[0][0])[idx] = s;
    }
    __syncthreads();

    float sq = 0.f;
    #pragma unroll
    for (int k = 0; k < 8; ++k) { float x = Tred[k][lane]; sq = fmaf(x, x, sq); }
    const float scale = sq / (1.0f + sq) / sqrtf(sq + 1e-9f);
    Hn[g][lane]     = f2bf(scale * Tred[g][lane]);
    Hn[g + 4][lane] = f2bf(scale * Tred[g + 4][lane]);
    __syncthreads();

    delta_phase(lnb, Hn, slots + ((size_t)(b & (NSLOT - 1)) << 12), g, m, q);
}

// ---------------------------------------------------------------------------
// Iterations 1/2: softmax, T = W @ ln (ILP-batched loads), squash,
// then delta -> slots (it1) or write out (it2).
__global__ __launch_bounds__(256, 4) void k_route2(
    const unsigned short* __restrict__ ln,   // [1024,512,64] bf16
    const float* __restrict__ Bc,            // [4096]
    float* __restrict__ slots,               // [NSLOT][4096], if !last
    const int* __restrict__ seq_len,         // [1024]
    float* __restrict__ out,                 // [1024,8,64] f32, if last
    int last)
{
    __shared__ __align__(16) float WsT[512][8];
    __shared__ __align__(16) float Tpart[4][8][64];
    __shared__ __align__(16) float Tred[8][64];
    __shared__ __align__(16) unsigned short Hn[8][64];

    const int t = threadIdx.x, lane = t & 63, g = t >> 6, b = blockIdx.x;
    const int m = lane & 15, q = lane >> 4;
    const int sl = seq_len[b];
    const unsigned short* lnb = ln + ((size_t)b << 15);

    softmax_to_WsT(Bc, sl, lane, g, WsT);
    __syncthreads();

    // ---- T-phase: 8 independent 8B loads in flight per batch --------------
    floatx4 Tacc[8];
    #pragma unroll
    for (int k = 0; k < 8; ++k) Tacc[k] = (floatx4){0.f, 0.f, 0.f, 0.f};
    const int l0 = g << 7;
    for (int ii = 0; ii < 4; ++ii) {
        uint2 u[8];
        #pragma unroll
        for (int j = 0; j < 8; ++j) {
            const int l = l0 + (ii << 5) + (j << 2) + q;
            u[j] = *(const uint2*)&lnb[(l << 6) + (m << 2)];
        }
        #pragma unroll
        for (int j = 0; j < 8; ++j) {
            const int l = l0 + (ii << 5) + (j << 2) + q;
            const float x0 = __uint_as_float(u[j].x << 16);
            const float x1 = __uint_as_float(u[j].x & 0xFFFF0000u);
            const float x2 = __uint_as_float(u[j].y << 16);
            const float x3 = __uint_as_float(u[j].y & 0xFFFF0000u);
            const float4 wa = *(const float4*)&WsT[l][0];
            const float4 wb = *(const float4*)&WsT[l][4];
#define TROW(K, WV)                                          \
            Tacc[K][0] = fmaf(WV, x0, Tacc[K][0]);           \
            Tacc[K][1] = fmaf(WV, x1, Tacc[K][1]);           \
            Tacc[K][2] = fmaf(WV, x2, Tacc[K][2]);           \
            Tacc[K][3] = fmaf(WV, x3, Tacc[K][3]);
            TROW(0, wa.x) TROW(1, wa.y) TROW(2, wa.z) TROW(3, wa.w)
            TROW(4, wb.x) TROW(5, wb.y) TROW(6, wb.z) TROW(7, wb.w)
#undef TROW
        }
    }
    #pragma unroll
    for (int k = 0; k < 8; ++k)
        #pragma unroll
        for (int j = 0; j < 4; ++j) {
            float v = Tacc[k][j];
            v += __shfl_xor(v, 16);
            v += __shfl_xor(v, 32);
            Tacc[k][j] = v;
        }
    if (q == 0) {
        #pragma unroll
        for (int k = 0; k < 8; ++k)
            *(float4*)&Tpart[g][k][m << 2] =
                make_float4(Tacc[k][0], Tacc[k][1], Tacc[k][2], Tacc[k][3]);
    }
    __syncthreads();

    #pragma unroll
    for (int idx = t; idx < 512; idx += 256) {
        float s = (&Tpart[0][0][0])[idx] + (&Tpart[1][0][0])[idx]
                + (&Tpart[2][0][0])[idx] + (&Tpart[3][0][0])[idx];
        (&Tred[0][0])[idx] = s;
    }
    __syncthreads();

    float sq = 0.f;
    #pragma unroll
    for (int k = 0; k < 8; ++k) { float x = Tred[k][lane]; sq = fmaf(x, x, sq); }
    const float scale = sq / (1.0f + sq) / sqrtf(sq + 1e-9f);
    const float hf0 = scale * Tred[g][lane];
    const float hf1 = scale * Tred[g + 4][lane];

    if (last) {
        out[(((size_t)b * 8 + g)     << 6) + lane] = hf0;
        out[(((size_t)b * 8 + g + 4) << 6) + lane] = hf1;
        return;
    }
    Hn[g][lane]     = f2bf(hf0);
    Hn[g + 4][lane] = f2bf(hf1);
    __syncthreads();

    delta_phase(lnb, Hn, slots + ((size_t)(b & (NSLOT - 1)) << 12), g, m, q);
}

// ===========================================================================
// Fallback (round-4 verified path) — used only if ws_size is too small.
__global__ __launch_bounds__(256) void k_copy4k(const float* __restrict__ src,
                                                float* __restrict__ dst) {
    int i = blockIdx.x * 256 + threadIdx.x;
    dst[i] = src[i];
}

__global__ __launch_bounds__(256, 4) void k_route(
    const float* __restrict__ low, const float* __restrict__ S,
    const float* __restrict__ Bcur, float* __restrict__ Bnext,
    const int* __restrict__ seq_len, float* __restrict__ out, int last)
{
    __shared__ float smemA[64 * 65];
    __shared__ float Spad[64][65];
    __shared__ float GT[64][8];
    __shared__ float Tred[8][64];
    float* WsT = smemA;
    float (*Tpart)[8][64] = (float (*)[8][64])smemA;
    float (*tile)[65]     = (float (*)[65])smemA;

    const int t = threadIdx.x, o = t & 63, g = t >> 6, b = blockIdx.x;
    const int sl = seq_len[b];
    const float* lowb = low + ((size_t)b << 15);

    #pragma unroll
    for (int i = 0; i < 16; ++i) {
        int idx = t + (i << 8);
        Spad[idx >> 6][idx & 63] = S[idx];
    }
    #pragma unroll
    for (int kk = 0; kk < 2; ++kk) {
        const int k = g + (kk << 2);
        float v[8];
        float mx = NEG_FILL;
        #pragma unroll
        for (int j = 0; j < 8; ++j) {
            int l = o + (j << 6);
            v[j] = (l < sl) ? Bcur[(k << 9) + l] : NEG_FILL;
            mx = fmaxf(mx, v[j]);
        }
        #pragma unroll
        for (int off = 32; off; off >>= 1) mx = fmaxf(mx, __shfl_xor(mx, off));
        float s = 0.f;
        #pragma unroll
        for (int j = 0; j < 8; ++j) { v[j] = expf(v[j] - mx); s += v[j]; }
        #pragma unroll
        for (int off = 32; off; off >>= 1) s += __shfl_xor(s, off);
        const float inv = 1.0f / s;
        #pragma unroll
        for (int j = 0; j < 8; ++j) WsT[((o + (j << 6)) << 3) + k] = v[j] * inv;
    }
    __syncthreads();

    float Ta[8];
    #pragma unroll
    for (int k = 0; k < 8; ++k) Ta[k] = 0.f;
    {
        const int l0 = g << 7;
        #pragma unroll 4
        for (int i = 0; i < 128; ++i) {
            const int l = l0 + i;
            const float x = lowb[(l << 6) + o];
            const float4 wa = *(const float4*)&WsT[(l << 3)];
            const float4 wb = *(const float4*)&WsT[(l << 3) + 4];
            Ta[0] = fmaf(wa.x, x, Ta[0]); Ta[1] = fmaf(wa.y, x, Ta[1]);
            Ta[2] = fmaf(wa.z, x, Ta[2]); Ta[3] = fmaf(wa.w, x, Ta[3]);
            Ta[4] = fmaf(wb.x, x, Ta[4]); Ta[5] = fmaf(wb.y, x, Ta[5]);
            Ta[6] = fmaf(wb.z, x, Ta[6]); Ta[7] = fmaf(wb.w, x, Ta[7]);
        }
    }
    __syncthreads();
    #pragma unroll
    for (int k = 0; k < 8; ++k) Tpart[g][k][o] = Ta[k];
    __syncthreads();

    float h0 = 0.f, h1 = 0.f;
    #pragma unroll
    for (int gg = 0; gg < 4; ++gg) { h0 += Tpart[gg][g][o]; h1 += Tpart[gg][g + 4][o]; }
    Tred[g][o] = h0; Tred[g + 4][o] = h1;
    __syncthreads();

    float hp0 = 0.f, hp1 = 0.f;
    #pragma unroll
    for (int d = 0; d < 64; ++d) {
        const float sv = Spad[d][o];
        hp0 = fmaf(Tred[g][d], sv, hp0);
        hp1 = fmaf(Tred[g + 4][d], sv, hp1);
    }
    __syncthreads();
    Tred[g][o] = hp0; Tred[g + 4][o] = hp1;
    __syncthreads();

    float sq = 0.f;
    #pragma unroll
    for (int k = 0; k < 8; ++k) { float x = Tred[k][o]; sq = fmaf(x, x, sq); }
    const float scale = sq / (1.0f + sq) / sqrtf(sq + 1e-9f);
    const float hf0 = scale * hp0;
    const float hf1 = scale * hp1;

    if (last) {
        out[(((size_t)b * 8 + g)     << 6) + o] = hf0;
        out[(((size_t)b * 8 + g + 4) << 6) + o] = hf1;
        return;
    }
    __syncthreads();
    Tred[g][o] = hf0; Tred[g + 4][o] = hf1;
    __syncthreads();

    float g0 = 0.f, g1 = 0.f;
    #pragma unroll
    for (int oo = 0; oo < 64; ++oo) {
        const float sv = Spad[o][oo];
        g0 = fmaf(Tred[g][oo], sv, g0);
        g1 = fmaf(Tred[g + 4][oo], sv, g1);
    }
    GT[o][g] = g0; GT[o][g + 4] = g1;
    __syncthreads();

    for (int c = 0; c < 8; ++c) {
        const int lc = c << 6;
        #pragma unroll
        for (int r = 0; r < 16; ++r) {
            const int lr = (g << 4) + r;
            tile[lr][o] = lowb[((lc + lr) << 6) + o];
        }
        __syncthreads();
        float a0 = 0.f, a1 = 0.f;
        #pragma unroll
        for (int d = 0; d < 64; ++d) {
            const float x = tile[o][d];
            a0 = fmaf(GT[d][g], x, a0);
            a1 = fmaf(GT[d][g + 4], x, a1);
        }
        atomicAdd(&Bnext[(g << 9) + lc + o], a0);
        atomicAdd(&Bnext[((g + 4) << 9) + lc + o], a1);
        __syncthreads();
    }
}

// ---------------------------------------------------------------------------
extern "C" void kernel_launch(void* const* d_in, const int* in_sizes, int n_in,
                              void* d_out, int out_size, void* d_ws, size_t ws_size,
                              hipStream_t stream) {
    const float* low   = (const float*)d_in[0];   // [1024,512,64]
    const float* Binit = (const float*)d_in[1];   // [1,8,512]
    const float* S     = (const float*)d_in[2];   // [64,64]
    const int*   seq   = (const int*)d_in[3];     // [1024,1]
    float* outp = (float*)d_out;                  // [1024,8,64] f32

    const size_t LN_BYTES   = (size_t)1024 * 512 * 64 * 2;        // 67.1 MB
    const size_t SLOT_BYTES = (size_t)NSLOT * 4096 * sizeof(float);
    const size_t NEED = LN_BYTES + SLOT_BYTES + 2 * 4096 * sizeof(float);

    if (ws_size >= NEED) {
        unsigned short* lnw = (unsigned short*)d_ws;
        float* slots = (float*)((char*)d_ws + LN_BYTES);
        float* B0 = slots + (size_t)NSLOT * 4096;
        float* B1 = B0 + 4096;

        k_init<<<(NSLOT * 4096) / 256, 256, 0, stream>>>(Binit, B0, slots);

        // iteration 0 (fused ln + route)
        k_fused0<<<1024, 256, 0, stream>>>(low, S, B0, slots, seq, lnw);
        k_bred<<<16, 256, 0, stream>>>(B0, B1, slots);

        // iteration 1
        k_route2<<<1024, 256, 0, stream>>>(lnw, B1, slots, seq, outp, 0);
        k_bred<<<16, 256, 0, stream>>>(B1, B0, slots);

        // iteration 2 (last)
        k_route2<<<1024, 256, 0, stream>>>(lnw, B0, nullptr, seq, outp, 1);
    } else {
        // fallback: round-4 verified path (ws >= 32 KB)
        float* B0 = (float*)d_ws;
        float* B1 = B0 + 4096;
        k_copy4k<<<16, 256, 0, stream>>>(Binit, B0);
        k_copy4k<<<16, 256, 0, stream>>>(B0, B1);
        k_route<<<1024, 256, 0, stream>>>(low, S, B0, B1, seq, outp, 0);
        k_copy4k<<<16, 256, 0, stream>>>(B1, B0);
        k_route<<<1024, 256, 0, stream>>>(low, S, B1, B0, seq, outp, 0);
        k_route<<<1024, 256, 0, stream>>>(low, S, B0, nullptr, seq, outp, 1);
    }
}